// Round 1
// baseline (257.406 us; speedup 1.0000x reference)
//
#include <hip/hip_runtime.h>
#include <cstdint>
#include <cstddef>

// Problem constants: B=8,S=2048,E=512,FFN=2048,Q=8
// M = B*S = 16384 rows, K = FFN = 2048, N = E = 512.

typedef __attribute__((ext_vector_type(8))) short s16x8;
typedef __attribute__((ext_vector_type(4))) float f32x4;

// round-to-nearest-even fp32 -> bf16
__device__ __forceinline__ unsigned short f2bf(float f) {
  unsigned int u = __float_as_uint(f);
  unsigned int r = u + 0x7fffu + ((u >> 16) & 1u);
  return (unsigned short)(r >> 16);
}

// async global->LDS, 16 B per lane. LDS dest is wave-uniform base + lane*16
// (HW does readfirstlane on the lds pointer), so chunks must be lane-ordered
// contiguous — they are (chunk id = wave*64 + lane).
__device__ __forceinline__ void async_copy16(const void* g, void* l) {
  __builtin_amdgcn_global_load_lds(
      (const __attribute__((address_space(1))) void*)(uintptr_t)g,
      (__attribute__((address_space(3))) void*)(unsigned int)(uintptr_t)l,
      16, 0, 0);
}

// ---------------------------------------------------------------------------
// Kernel 1: act[r][f] = bf16(relu(sum_q cos(x[r][q])cos(ry[q]) * w1[f][q] + b1[f]))
// one block per row; thread t computes f = t*8 .. t*8+7 (16 B coalesced store)
// ---------------------------------------------------------------------------
__global__ __launch_bounds__(256) void k_act(
    const float* __restrict__ x, const float* __restrict__ ry,
    const float* __restrict__ w1, const float* __restrict__ b1,
    unsigned short* __restrict__ act) {
  __shared__ float zsh[8];
  const int r = blockIdx.x;
  const int t = threadIdx.x;
  if (t < 8) zsh[t] = __cosf(x[(size_t)r * 512 + t]) * __cosf(ry[t]);
  __syncthreads();
  float z[8];
#pragma unroll
  for (int q = 0; q < 8; ++q) z[q] = zsh[q];
  const int f0 = t * 8;
  unsigned short o[8];
#pragma unroll
  for (int i = 0; i < 8; ++i) {
    const float* wr = w1 + (size_t)(f0 + i) * 8;
    float4 a = *(const float4*)wr;
    float4 b = *(const float4*)(wr + 4);
    float h = b1[f0 + i];
    h += z[0] * a.x + z[1] * a.y + z[2] * a.z + z[3] * a.w;
    h += z[4] * b.x + z[5] * b.y + z[6] * b.z + z[7] * b.w;
    h = fmaxf(h, 0.0f);
    o[i] = f2bf(h);
  }
  uint4 pack;
  pack.x = o[0] | ((unsigned)o[1] << 16);
  pack.y = o[2] | ((unsigned)o[3] << 16);
  pack.z = o[4] | ((unsigned)o[5] << 16);
  pack.w = o[6] | ((unsigned)o[7] << 16);
  *(uint4*)(act + (size_t)r * 2048 + f0) = pack;
}

// ---------------------------------------------------------------------------
// Kernel 2: w2 (fp32 [512][2048]) -> bf16 same layout
// ---------------------------------------------------------------------------
__global__ __launch_bounds__(256) void k_w2(const float* __restrict__ w2,
                                            unsigned short* __restrict__ w2b) {
  size_t i = ((size_t)blockIdx.x * 256 + threadIdx.x) * 4;
  float4 v = *(const float4*)(w2 + i);
  uint2 p;
  p.x = f2bf(v.x) | ((unsigned)f2bf(v.y) << 16);
  p.y = f2bf(v.z) | ((unsigned)f2bf(v.w) << 16);
  *(uint2*)(w2b + i) = p;
}

// ---------------------------------------------------------------------------
// Kernel 3: C[m][n] = sum_k A[m][k]*Bw[n][k] + b2[n]   (gemm_bt, m97 structure)
// A = act bf16 [rows][2048] K-contig, Bw = w2b bf16 [512][2048] K-contig.
// 128x128 tile, BK=32, 256 threads = 4 waves in 2x2, 4x4 frags of 16x16x32.
// Staging: 4x global_load_lds dwordx4 per thread per K-iter, 2-barrier loop.
// ---------------------------------------------------------------------------
__global__ __launch_bounds__(256) void k_gemm(
    const unsigned short* __restrict__ A, const unsigned short* __restrict__ Bw,
    const float* __restrict__ b2, float* __restrict__ C) {
  __shared__ unsigned short As[128 * 32];  // [m][k], 64 B rows
  __shared__ unsigned short Bs[128 * 32];  // [n][k]
  const int t = threadIdx.x;
  const int lane = t & 63;
  const int w = t >> 6;
  const int nt = blockIdx.x & 3;
  const int mt = blockIdx.x >> 2;
  const int r0 = mt * 128;
  const int c0 = nt * 128;

  // staging: tile = 512 chunks of 16 B; chunk c -> m = c>>2, kq = c&3
  const int cA1 = t, cA2 = t + 256;
  const unsigned short* gA1 = A + (size_t)(r0 + (cA1 >> 2)) * 2048 + (cA1 & 3) * 8;
  const unsigned short* gA2 = A + (size_t)(r0 + (cA2 >> 2)) * 2048 + (cA2 & 3) * 8;
  const unsigned short* gB1 = Bw + (size_t)(c0 + (cA1 >> 2)) * 2048 + (cA1 & 3) * 8;
  const unsigned short* gB2 = Bw + (size_t)(c0 + (cA2 >> 2)) * 2048 + (cA2 & 3) * 8;
  char* lA1 = (char*)As + cA1 * 16;
  char* lA2 = (char*)As + cA2 * 16;
  char* lB1 = (char*)Bs + cA1 * 16;
  char* lB2 = (char*)Bs + cA2 * 16;

  const int wm = (w >> 1) * 64;
  const int wn = (w & 1) * 64;
  const int fr = lane & 15;
  const int quad = lane >> 4;

  f32x4 acc[4][4];
#pragma unroll
  for (int i = 0; i < 4; ++i)
#pragma unroll
    for (int j = 0; j < 4; ++j) acc[i][j] = (f32x4){0.f, 0.f, 0.f, 0.f};

  // A-operand frag: lane holds A[m = wm + i*16 + fr][k = quad*8 + j], 8 contig k
  const unsigned short* pAf = As + (wm + fr) * 32 + quad * 8;
  const unsigned short* pBf = Bs + (wn + fr) * 32 + quad * 8;

  for (int kt = 0; kt < 64; ++kt) {
    async_copy16(gA1, lA1);
    async_copy16(gA2, lA2);
    async_copy16(gB1, lB1);
    async_copy16(gB2, lB2);
    gA1 += 32; gA2 += 32; gB1 += 32; gB2 += 32;
    __syncthreads();  // compiler emits s_waitcnt vmcnt(0) before s_barrier
    s16x8 af[4], bf[4];
#pragma unroll
    for (int i = 0; i < 4; ++i) af[i] = *(const s16x8*)(pAf + i * 16 * 32);
#pragma unroll
    for (int j = 0; j < 4; ++j) bf[j] = *(const s16x8*)(pBf + j * 16 * 32);
#pragma unroll
    for (int i = 0; i < 4; ++i)
#pragma unroll
      for (int j = 0; j < 4; ++j)
        acc[i][j] = __builtin_amdgcn_mfma_f32_16x16x32_bf16(af[i], bf[j],
                                                            acc[i][j], 0, 0, 0);
    __syncthreads();
  }

  // epilogue: C/D layout col = lane&15, row = quad*4 + reg  (m89/m91 verified)
  float bias[4];
#pragma unroll
  for (int j = 0; j < 4; ++j) bias[j] = b2[c0 + wn + j * 16 + fr];
#pragma unroll
  for (int i = 0; i < 4; ++i) {
    const int rbase = r0 + wm + i * 16 + quad * 4;
#pragma unroll
    for (int rr = 0; rr < 4; ++rr) {
      float* crow = C + (size_t)(rbase + rr) * 512;
#pragma unroll
      for (int j = 0; j < 4; ++j)
        crow[c0 + wn + j * 16 + fr] = acc[i][j][rr] + bias[j];
    }
  }
}

// ---------------------------------------------------------------------------
// Emergency fallback (only if ws_size is tiny): fully fused fp32, 1 row/block.
// Correct but slow (~ms); should never run if ws is reasonable.
// ---------------------------------------------------------------------------
__global__ __launch_bounds__(256) void k_naive(
    const float* __restrict__ x, const float* __restrict__ ry,
    const float* __restrict__ w1, const float* __restrict__ b1,
    const float* __restrict__ w2, const float* __restrict__ b2,
    float* __restrict__ out) {
  __shared__ float zsh[8];
  __shared__ float acts[2048];
  const int r = blockIdx.x;
  const int t = threadIdx.x;
  if (t < 8) zsh[t] = __cosf(x[(size_t)r * 512 + t]) * __cosf(ry[t]);
  __syncthreads();
  float z[8];
#pragma unroll
  for (int q = 0; q < 8; ++q) z[q] = zsh[q];
#pragma unroll
  for (int i = 0; i < 8; ++i) {
    const int f = t * 8 + i;
    const float* wr = w1 + (size_t)f * 8;
    float4 a = *(const float4*)wr;
    float4 b = *(const float4*)(wr + 4);
    float h = b1[f] + z[0] * a.x + z[1] * a.y + z[2] * a.z + z[3] * a.w +
              z[4] * b.x + z[5] * b.y + z[6] * b.z + z[7] * b.w;
    acts[f] = fmaxf(h, 0.0f);
  }
  __syncthreads();
  for (int ee = 0; ee < 2; ++ee) {
    const int e = t + ee * 256;
    const float* wr = w2 + (size_t)e * 2048;
    float acc = b2[e];
    for (int f = 0; f < 2048; f += 4) {
      float4 wv = *(const float4*)(wr + f);
      float4 av = *(const float4*)(acts + f);
      acc += av.x * wv.x + av.y * wv.y + av.z * wv.z + av.w * wv.w;
    }
    out[(size_t)r * 512 + e] = acc;
  }
}

extern "C" void kernel_launch(void* const* d_in, const int* in_sizes, int n_in,
                              void* d_out, int out_size, void* d_ws,
                              size_t ws_size, hipStream_t stream) {
  const float* x  = (const float*)d_in[0];
  const float* ry = (const float*)d_in[1];
  const float* w1 = (const float*)d_in[2];
  const float* b1 = (const float*)d_in[3];
  const float* w2 = (const float*)d_in[4];
  const float* b2 = (const float*)d_in[5];
  float* out = (float*)d_out;

  const size_t M = 16384;
  const size_t w2b_bytes = (size_t)512 * 2048 * 2;  // 2 MB bf16 w2

  size_t chunk = 0;
  if (ws_size > w2b_bytes)
    chunk = ((ws_size - w2b_bytes) / ((size_t)2048 * 2)) & ~(size_t)127;
  if (chunk == 0) {
    k_naive<<<dim3(16384), dim3(256), 0, stream>>>(x, ry, w1, b1, w2, b2, out);
    return;
  }
  if (chunk > M) chunk = M;

  unsigned short* w2b = (unsigned short*)d_ws;
  unsigned short* act = (unsigned short*)((char*)d_ws + w2b_bytes);

  k_w2<<<dim3(1024), dim3(256), 0, stream>>>(w2, w2b);
  for (size_t r0 = 0; r0 < M; r0 += chunk) {
    const size_t rows = (M - r0 < chunk) ? (M - r0) : chunk;
    k_act<<<dim3((unsigned)rows), dim3(256), 0, stream>>>(x + r0 * 512, ry, w1,
                                                          b1, act);
    k_gemm<<<dim3((unsigned)(rows / 128) * 4), dim3(256), 0, stream>>>(
        act, w2b, b2, out + r0 * 512);
  }
}

// Round 2
// 155.050 us; speedup vs baseline: 1.6601x; 1.6601x over previous
//
#include <hip/hip_runtime.h>
#include <cstdint>
#include <cstddef>

// Problem constants: B=8,S=2048,E=512,FFN=2048,Q=8
// M = B*S = 16384 rows, K = FFN = 2048, N = E = 512.

typedef __attribute__((ext_vector_type(8))) short s16x8;
typedef __attribute__((ext_vector_type(4))) float f32x4;

// round-to-nearest-even fp32 -> bf16
__device__ __forceinline__ unsigned short f2bf(float f) {
  unsigned int u = __float_as_uint(f);
  unsigned int r = u + 0x7fffu + ((u >> 16) & 1u);
  return (unsigned short)(r >> 16);
}

__device__ __forceinline__ void async_copy16(const void* g, void* l) {
  __builtin_amdgcn_global_load_lds(
      (const __attribute__((address_space(1))) void*)(uintptr_t)g,
      (__attribute__((address_space(3))) void*)(unsigned int)(uintptr_t)l,
      16, 0, 0);
}

// ---------------------------------------------------------------------------
// Kernel 1 (rewritten): act[r][f] = bf16(relu(z[r]·w1[f] + b1[f]))
// 32 rows per block. Thread t owns f = t*8..t*8+7; w1/b1 held in REGISTERS
// (loaded once, amortized over 32 rows — kills the per-row L1-thrash that
// made R0's version 133 us). z for the block's 32 rows staged in LDS.
// Stores: uint4 per thread, lane-consecutive -> 1 KB/wave coalesced.
// ---------------------------------------------------------------------------
__global__ __launch_bounds__(256) void k_act(
    const float* __restrict__ x, const float* __restrict__ ry,
    const float* __restrict__ w1, const float* __restrict__ b1,
    unsigned short* __restrict__ act) {
  __shared__ float zsh[32][8];
  const int t = threadIdx.x;
  const int r0 = blockIdx.x * 32;

  // z staging: 32 rows x 8 qubits = 256 elements, one per thread
  {
    const int row = t >> 3, q = t & 7;
    zsh[row][q] = __cosf(x[(size_t)(r0 + row) * 512 + q]) * __cosf(ry[q]);
  }

  // w1 rows f0..f0+7 into registers (64 floats) + b1 (8 floats)
  const int f0 = t * 8;
  float4 wv[16];  // wv[2*i], wv[2*i+1] = w1[f0+i][0..3], [4..7]
#pragma unroll
  for (int i = 0; i < 8; ++i) {
    const float* wr = w1 + (size_t)(f0 + i) * 8;
    wv[2 * i] = *(const float4*)wr;
    wv[2 * i + 1] = *(const float4*)(wr + 4);
  }
  float bb[8];
  {
    float4 b0 = *(const float4*)(b1 + f0);
    float4 b4 = *(const float4*)(b1 + f0 + 4);
    bb[0] = b0.x; bb[1] = b0.y; bb[2] = b0.z; bb[3] = b0.w;
    bb[4] = b4.x; bb[5] = b4.y; bb[6] = b4.z; bb[7] = b4.w;
  }
  __syncthreads();

#pragma unroll 4
  for (int row = 0; row < 32; ++row) {
    float z[8];
#pragma unroll
    for (int q = 0; q < 8; ++q) z[q] = zsh[row][q];  // LDS broadcast (free)
    unsigned short o[8];
#pragma unroll
    for (int i = 0; i < 8; ++i) {
      float4 a = wv[2 * i], b = wv[2 * i + 1];
      float h = bb[i];
      h += z[0] * a.x + z[1] * a.y + z[2] * a.z + z[3] * a.w;
      h += z[4] * b.x + z[5] * b.y + z[6] * b.z + z[7] * b.w;
      o[i] = f2bf(fmaxf(h, 0.0f));
    }
    uint4 pack;
    pack.x = o[0] | ((unsigned)o[1] << 16);
    pack.y = o[2] | ((unsigned)o[3] << 16);
    pack.z = o[4] | ((unsigned)o[5] << 16);
    pack.w = o[6] | ((unsigned)o[7] << 16);
    *(uint4*)(act + (size_t)(r0 + row) * 2048 + f0) = pack;
  }
}

// ---------------------------------------------------------------------------
// Kernel 2: w2 (fp32 [512][2048]) -> bf16 same layout
// ---------------------------------------------------------------------------
__global__ __launch_bounds__(256) void k_w2(const float* __restrict__ w2,
                                            unsigned short* __restrict__ w2b) {
  size_t i = ((size_t)blockIdx.x * 256 + threadIdx.x) * 4;
  float4 v = *(const float4*)(w2 + i);
  uint2 p;
  p.x = f2bf(v.x) | ((unsigned)f2bf(v.y) << 16);
  p.y = f2bf(v.z) | ((unsigned)f2bf(v.w) << 16);
  *(uint2*)(w2b + i) = p;
}

// ---------------------------------------------------------------------------
// Kernel 3: C[m][n] = sum_k A[m][k]*Bw[n][k] + b2[n]   (gemm_bt, m97 structure)
// XCD swizzle: mt = bid % 128, nt = bid / 128 -> the 4 blocks sharing an
// A-tile have ids {mt, mt+128, mt+256, mt+384} === mt (mod 8) -> same XCD
// under round-robin dispatch -> A fetched ~once from HBM, not 4x.
// ---------------------------------------------------------------------------
__global__ __launch_bounds__(256) void k_gemm(
    const unsigned short* __restrict__ A, const unsigned short* __restrict__ Bw,
    const float* __restrict__ b2, float* __restrict__ C) {
  __shared__ unsigned short As[128 * 32];  // [m][k], 64 B rows
  __shared__ unsigned short Bs[128 * 32];  // [n][k]
  const int t = threadIdx.x;
  const int lane = t & 63;
  const int w = t >> 6;
  const int nblk_m = gridDim.x >> 2;       // rows/128
  const int mt = blockIdx.x % nblk_m;
  const int nt = blockIdx.x / nblk_m;
  const int r0 = mt * 128;
  const int c0 = nt * 128;

  // staging: tile = 512 chunks of 16 B; chunk c -> m = c>>2, kq = c&3
  const int cA1 = t, cA2 = t + 256;
  const unsigned short* gA1 = A + (size_t)(r0 + (cA1 >> 2)) * 2048 + (cA1 & 3) * 8;
  const unsigned short* gA2 = A + (size_t)(r0 + (cA2 >> 2)) * 2048 + (cA2 & 3) * 8;
  const unsigned short* gB1 = Bw + (size_t)(c0 + (cA1 >> 2)) * 2048 + (cA1 & 3) * 8;
  const unsigned short* gB2 = Bw + (size_t)(c0 + (cA2 >> 2)) * 2048 + (cA2 & 3) * 8;
  char* lA1 = (char*)As + cA1 * 16;
  char* lA2 = (char*)As + cA2 * 16;
  char* lB1 = (char*)Bs + cA1 * 16;
  char* lB2 = (char*)Bs + cA2 * 16;

  const int wm = (w >> 1) * 64;
  const int wn = (w & 1) * 64;
  const int fr = lane & 15;
  const int quad = lane >> 4;

  f32x4 acc[4][4];
#pragma unroll
  for (int i = 0; i < 4; ++i)
#pragma unroll
    for (int j = 0; j < 4; ++j) acc[i][j] = (f32x4){0.f, 0.f, 0.f, 0.f};

  const unsigned short* pAf = As + (wm + fr) * 32 + quad * 8;
  const unsigned short* pBf = Bs + (wn + fr) * 32 + quad * 8;

  for (int kt = 0; kt < 64; ++kt) {
    async_copy16(gA1, lA1);
    async_copy16(gA2, lA2);
    async_copy16(gB1, lB1);
    async_copy16(gB2, lB2);
    gA1 += 32; gA2 += 32; gB1 += 32; gB2 += 32;
    __syncthreads();
    s16x8 af[4], bf[4];
#pragma unroll
    for (int i = 0; i < 4; ++i) af[i] = *(const s16x8*)(pAf + i * 16 * 32);
#pragma unroll
    for (int j = 0; j < 4; ++j) bf[j] = *(const s16x8*)(pBf + j * 16 * 32);
#pragma unroll
    for (int i = 0; i < 4; ++i)
#pragma unroll
      for (int j = 0; j < 4; ++j)
        acc[i][j] = __builtin_amdgcn_mfma_f32_16x16x32_bf16(af[i], bf[j],
                                                            acc[i][j], 0, 0, 0);
    __syncthreads();
  }

  // epilogue: C/D layout col = lane&15, row = quad*4 + reg  (m89/m91 verified)
  float bias[4];
#pragma unroll
  for (int j = 0; j < 4; ++j) bias[j] = b2[c0 + wn + j * 16 + fr];
#pragma unroll
  for (int i = 0; i < 4; ++i) {
    const int rbase = r0 + wm + i * 16 + quad * 4;
#pragma unroll
    for (int rr = 0; rr < 4; ++rr) {
      float* crow = C + (size_t)(rbase + rr) * 512;
#pragma unroll
      for (int j = 0; j < 4; ++j)
        crow[c0 + wn + j * 16 + fr] = acc[i][j][rr] + bias[j];
    }
  }
}

// ---------------------------------------------------------------------------
// Emergency fallback (only if ws_size is tiny): fully fused fp32, 1 row/block.
// ---------------------------------------------------------------------------
__global__ __launch_bounds__(256) void k_naive(
    const float* __restrict__ x, const float* __restrict__ ry,
    const float* __restrict__ w1, const float* __restrict__ b1,
    const float* __restrict__ w2, const float* __restrict__ b2,
    float* __restrict__ out) {
  __shared__ float zsh[8];
  __shared__ float acts[2048];
  const int r = blockIdx.x;
  const int t = threadIdx.x;
  if (t < 8) zsh[t] = __cosf(x[(size_t)r * 512 + t]) * __cosf(ry[t]);
  __syncthreads();
  float z[8];
#pragma unroll
  for (int q = 0; q < 8; ++q) z[q] = zsh[q];
#pragma unroll
  for (int i = 0; i < 8; ++i) {
    const int f = t * 8 + i;
    const float* wr = w1 + (size_t)f * 8;
    float4 a = *(const float4*)wr;
    float4 b = *(const float4*)(wr + 4);
    float h = b1[f] + z[0] * a.x + z[1] * a.y + z[2] * a.z + z[3] * a.w +
              z[4] * b.x + z[5] * b.y + z[6] * b.z + z[7] * b.w;
    acts[f] = fmaxf(h, 0.0f);
  }
  __syncthreads();
  for (int ee = 0; ee < 2; ++ee) {
    const int e = t + ee * 256;
    const float* wr = w2 + (size_t)e * 2048;
    float acc = b2[e];
    for (int f = 0; f < 2048; f += 4) {
      float4 wv = *(const float4*)(wr + f);
      float4 av = *(const float4*)(acts + f);
      acc += av.x * wv.x + av.y * wv.y + av.z * wv.z + av.w * wv.w;
    }
    out[(size_t)r * 512 + e] = acc;
  }
}

extern "C" void kernel_launch(void* const* d_in, const int* in_sizes, int n_in,
                              void* d_out, int out_size, void* d_ws,
                              size_t ws_size, hipStream_t stream) {
  const float* x  = (const float*)d_in[0];
  const float* ry = (const float*)d_in[1];
  const float* w1 = (const float*)d_in[2];
  const float* b1 = (const float*)d_in[3];
  const float* w2 = (const float*)d_in[4];
  const float* b2 = (const float*)d_in[5];
  float* out = (float*)d_out;

  const size_t M = 16384;
  const size_t w2b_bytes = (size_t)512 * 2048 * 2;  // 2 MB bf16 w2

  size_t chunk = 0;
  if (ws_size > w2b_bytes)
    chunk = ((ws_size - w2b_bytes) / ((size_t)2048 * 2)) & ~(size_t)127;
  if (chunk == 0) {
    k_naive<<<dim3(16384), dim3(256), 0, stream>>>(x, ry, w1, b1, w2, b2, out);
    return;
  }
  if (chunk > M) chunk = M;

  unsigned short* w2b = (unsigned short*)d_ws;
  unsigned short* act = (unsigned short*)((char*)d_ws + w2b_bytes);

  k_w2<<<dim3(1024), dim3(256), 0, stream>>>(w2, w2b);
  for (size_t r0 = 0; r0 < M; r0 += chunk) {
    const size_t rows = (M - r0 < chunk) ? (M - r0) : chunk;
    k_act<<<dim3((unsigned)(rows / 32)), dim3(256), 0, stream>>>(
        x + r0 * 512, ry, w1, b1, act);
    k_gemm<<<dim3((unsigned)(rows / 128) * 4), dim3(256), 0, stream>>>(
        act, w2b, b2, out + r0 * 512);
  }
}